// Round 12
// baseline (289.918 us; speedup 1.0000x reference)
//
#include <hip/hip_runtime.h>
#include <hip/hip_bf16.h>

typedef short bf16x8_t __attribute__((ext_vector_type(8)));
typedef float f32x4_t __attribute__((ext_vector_type(4)));

#define SDIM 2048
#define DDIM 64
#define KBLK 64
#define NIT  (SDIM / KBLK)
#define NBH  48

__device__ __forceinline__ unsigned short f2bf(float f) {
    return __builtin_bit_cast(unsigned short, (__bf16)f);
}
__device__ __forceinline__ unsigned int pack2(float lo, float hi) {
    return ((unsigned int)f2bf(hi) << 16) | (unsigned int)f2bf(lo);
}
__device__ __forceinline__ bf16x8_t pack8(f32x4_t a, f32x4_t b) {
    bf16x8_t r;
    r[0] = (short)f2bf(a[0]); r[1] = (short)f2bf(a[1]);
    r[2] = (short)f2bf(a[2]); r[3] = (short)f2bf(a[3]);
    r[4] = (short)f2bf(b[0]); r[5] = (short)f2bf(b[1]);
    r[6] = (short)f2bf(b[2]); r[7] = (short)f2bf(b[3]);
    return r;
}
__device__ __forceinline__ bf16x8_t pack8s(f32x4_t a, f32x4_t b, float s) {
    bf16x8_t r;
    r[0] = (short)f2bf(a[0] * s); r[1] = (short)f2bf(a[1] * s);
    r[2] = (short)f2bf(a[2] * s); r[3] = (short)f2bf(a[3] * s);
    r[4] = (short)f2bf(b[0] * s); r[5] = (short)f2bf(b[1] * s);
    r[6] = (short)f2bf(b[2] * s); r[7] = (short)f2bf(b[3] * s);
    return r;
}
struct uint4s { unsigned int x, y, z, w; };

__device__ __forceinline__ void lds_sync() {
    asm volatile("s_waitcnt lgkmcnt(0)" ::: "memory");
    __builtin_amdgcn_s_barrier();
    asm volatile("" ::: "memory");
}

// ---------- prep 1: K fp32 -> bf16 (row-major) ----------
__global__ __launch_bounds__(256) void cvt_k_kernel(const float* __restrict__ K,
                                                    unsigned short* __restrict__ Kb) {
    size_t i = ((size_t)blockIdx.x * 256 + threadIdx.x) * 8;
    f32x4_t a = *(const f32x4_t*)(K + i);
    f32x4_t b = *(const f32x4_t*)(K + i + 4);
    *(bf16x8_t*)(Kb + i) = pack8(a, b);
}

// ---------- prep 2: V fp32 [bh][k][d] -> bf16 V^T [bh][d][k] ----------
__global__ __launch_bounds__(256) void tr_v_kernel(const float* __restrict__ V,
                                                   unsigned short* __restrict__ VT) {
    __shared__ unsigned short lt[64 * 72];
    const int bh = blockIdx.x >> 5;
    const int kt = blockIdx.x & 31;
    const float* Vb = V + (size_t)bh * (SDIM * DDIM) + (size_t)kt * 64 * DDIM;
    unsigned short* VTb = VT + (size_t)bh * (DDIM * SDIM) + kt * 64;
    const int t = threadIdx.x;
    {
        const int kl = t >> 2, dg = t & 3;
        const float* vp = Vb + kl * DDIM + dg * 16;
        f32x4_t v0 = *(const f32x4_t*)vp;
        f32x4_t v1 = *(const f32x4_t*)(vp + 4);
        f32x4_t v2 = *(const f32x4_t*)(vp + 8);
        f32x4_t v3 = *(const f32x4_t*)(vp + 12);
#pragma unroll
        for (int j = 0; j < 16; ++j) {
            float f = (j < 4) ? v0[j] : (j < 8) ? v1[j - 4] : (j < 12) ? v2[j - 8] : v3[j - 12];
            lt[(dg * 16 + j) * 72 + kl] = f2bf(f);
        }
    }
    __syncthreads();
    {
        const int d = t >> 2, kg = t & 3;
        bf16x8_t w0 = *(const bf16x8_t*)&lt[d * 72 + kg * 16];
        bf16x8_t w1 = *(const bf16x8_t*)&lt[d * 72 + kg * 16 + 8];
        *(bf16x8_t*)(VTb + (size_t)d * SDIM + kg * 16) = w0;
        *(bf16x8_t*)(VTb + (size_t)d * SDIM + kg * 16 + 8) = w1;
    }
}

// ---------- main: 128 q/block, dbuf LDS staging, XCD-local bh mapping ----------
__global__ __launch_bounds__(256, 2) void sdpa_main_kernel(
    const float* __restrict__ Q, const unsigned short* __restrict__ Kb,
    const unsigned short* __restrict__ VT, float* __restrict__ out,
    float* __restrict__ attn)
{
    __shared__ __align__(16) unsigned short Klds[2][KBLK * DDIM];  // 2 x 8KB
    __shared__ __align__(16) unsigned short Vlds[2][KBLK * DDIM];  // 2 x 8KB
    __shared__ __align__(16) float pbuf[4][16 * 64];               // 16KB

    const int bid = blockIdx.x;
    // XCD-aware mapping (T1): 48 % 8 == 0, so all 16 blocks of a bh land on
    // XCD bh%8 -> each XCD's L2 holds 6 bh x 512KB = 3MB working set.
    const int qt  = bid / NBH;     // 0..15
    const int bh  = bid - qt * NBH;
    const int tid = threadIdx.x;
    const int lane = tid & 63;
    const int wv   = tid >> 6;     // 0..3
    const int l15  = lane & 15;
    const int hi   = lane >> 4;    // 0..3
    const int qbase = qt * 128 + wv * 32;

    const unsigned short* KbB = Kb + (size_t)bh * (SDIM * DDIM);
    const unsigned short* VTb = VT + (size_t)bh * (DDIM * SDIM);
    float* outW  = out  + ((size_t)bh * SDIM + qbase) * DDIM;
    float* attnW = attn + (size_t)bh * SDIM * SDIM + (size_t)qbase * SDIM;
    float* pb = pbuf[wv];

    const float SC = 0.18033688011112042f;  // (1/sqrt(64)) * log2(e)

    // ---- Q fragments (B operand), 2 sub-tiles, pre-scaled by SC
    const float* qp0 = Q + ((size_t)bh * SDIM + qbase + l15) * DDIM + hi * 8;
    const float* qp1 = qp0 + (size_t)16 * DDIM;
    const bf16x8_t aq0_0 = pack8s(*(const f32x4_t*)qp0,        *(const f32x4_t*)(qp0 + 4), SC);
    const bf16x8_t aq1_0 = pack8s(*(const f32x4_t*)(qp0 + 32), *(const f32x4_t*)(qp0 + 36), SC);
    const bf16x8_t aq0_1 = pack8s(*(const f32x4_t*)qp1,        *(const f32x4_t*)(qp1 + 4), SC);
    const bf16x8_t aq1_1 = pack8s(*(const f32x4_t*)(qp1 + 32), *(const f32x4_t*)(qp1 + 36), SC);

    // ---- staging helpers (contiguous full-line global access; 256 threads)
    auto stage_load_K = [&](int kbase, bf16x8_t kreg[2]) {
#pragma unroll
        for (int j = 0; j < 2; ++j)
            kreg[j] = *(const bf16x8_t*)(KbB + (size_t)kbase * DDIM + (j * 256 + tid) * 8);
    };
    auto stage_write_K = [&](unsigned short* dst, const bf16x8_t kreg[2]) {
#pragma unroll
        for (int j = 0; j < 2; ++j) {
            const int b = (j * 256 + tid) * 16;
            const int row = b >> 7;
            *(bf16x8_t*)((char*)dst + (b ^ ((row & 7) << 4))) = kreg[j];
        }
    };
    auto stage_load_V = [&](int kbase, bf16x8_t vreg[2]) {
#pragma unroll
        for (int j = 0; j < 2; ++j) {
            const int row = j * 32 + (tid >> 3);
            vreg[j] = *(const bf16x8_t*)(VTb + (size_t)row * SDIM + kbase + (tid & 7) * 8);
        }
    };
    auto stage_write_V = [&](unsigned short* dst, const bf16x8_t vreg[2]) {
#pragma unroll
        for (int j = 0; j < 2; ++j) {
            const int row = j * 32 + (tid >> 3);
            const int b = row * 128 + (tid & 7) * 16;
            *(bf16x8_t*)((char*)dst + (b ^ ((row & 7) << 4))) = vreg[j];
        }
    };
    auto read_tile = [&](const unsigned short* src, int s, int c) -> bf16x8_t {
        const int row = s * 16 + l15;
        const int b = row * 128 + c * 64 + hi * 16;
        return *(const bf16x8_t*)((const char*)src + (b ^ ((row & 7) << 4)));
    };

    // ================= pass A: row sums (K staged, dbuf, 1 barrier/iter) =================
    float rs0 = 0.f, rs1 = 0.f;
    {
        bf16x8_t kreg[2];
        stage_load_K(0, kreg);
        stage_write_K(Klds[0], kreg);
        lds_sync();
        for (int kb = 0; kb < NIT; ++kb) {
            bf16x8_t knx[2];
            if (kb + 1 < NIT) stage_load_K((kb + 1) * KBLK, knx);
            const unsigned short* Kc = Klds[kb & 1];
#pragma unroll
            for (int s = 0; s < 4; ++s) {
                bf16x8_t k0 = read_tile(Kc, s, 0), k1 = read_tile(Kc, s, 1);
                f32x4_t a0 = {0.f,0.f,0.f,0.f}, a1 = {0.f,0.f,0.f,0.f};
                a0 = __builtin_amdgcn_mfma_f32_16x16x32_bf16(k0, aq0_0, a0, 0, 0, 0);
                a0 = __builtin_amdgcn_mfma_f32_16x16x32_bf16(k1, aq1_0, a0, 0, 0, 0);
                a1 = __builtin_amdgcn_mfma_f32_16x16x32_bf16(k0, aq0_1, a1, 0, 0, 0);
                a1 = __builtin_amdgcn_mfma_f32_16x16x32_bf16(k1, aq1_1, a1, 0, 0, 0);
                rs0 += __builtin_amdgcn_exp2f(a0[0]) + __builtin_amdgcn_exp2f(a0[1])
                     + __builtin_amdgcn_exp2f(a0[2]) + __builtin_amdgcn_exp2f(a0[3]);
                rs1 += __builtin_amdgcn_exp2f(a1[0]) + __builtin_amdgcn_exp2f(a1[1])
                     + __builtin_amdgcn_exp2f(a1[2]) + __builtin_amdgcn_exp2f(a1[3]);
            }
            if (kb + 1 < NIT) stage_write_K(Klds[(kb + 1) & 1], knx);
            lds_sync();
        }
    }
    rs0 += __shfl_xor(rs0, 16); rs0 += __shfl_xor(rs0, 32);
    rs1 += __shfl_xor(rs1, 16); rs1 += __shfl_xor(rs1, 32);
    const float nlg0 = __builtin_amdgcn_logf(rs0);
    const float nlg1 = __builtin_amdgcn_logf(rs1);

    // ================= pass B (dbuf K+V, 1 barrier/iter) =================
    f32x4_t oacc0[4] = {{0.f,0.f,0.f,0.f},{0.f,0.f,0.f,0.f},{0.f,0.f,0.f,0.f},{0.f,0.f,0.f,0.f}};
    f32x4_t oacc1[4] = {{0.f,0.f,0.f,0.f},{0.f,0.f,0.f,0.f},{0.f,0.f,0.f,0.f},{0.f,0.f,0.f,0.f}};

    const int laneA = l15 + ((hi & 1) << 5);
    const int laneB = laneA + 16;
    const bool selHi = (hi >> 1) != 0;

    // p transpose-store through pbuf: full-line global writes (R10-verified)
    auto store_sub = [&](const f32x4_t P[4], int t, int kbase) {
#pragma unroll
        for (int g = 0; g < 4; ++g) {
            const int c4 = (g * 4 + hi) ^ ((l15 & 7) << 1);
            *(f32x4_t*)(pb + l15 * 64 + c4 * 4) = P[g];
        }
        asm volatile("s_waitcnt lgkmcnt(0)" ::: "memory");
        __builtin_amdgcn_sched_barrier(0);
#pragma unroll
        for (int j = 0; j < 4; ++j) {
            const int row = j * 4 + (lane & 3);
            const int c4 = lane >> 2;
            f32x4_t v = *(const f32x4_t*)(pb + row * 64 + (c4 ^ ((row & 7) << 1)) * 4);
            __builtin_nontemporal_store(v,
                (f32x4_t*)(attnW + (size_t)(t * 16 + row) * SDIM + kbase + c4 * 4));
        }
        asm volatile("s_waitcnt lgkmcnt(0)" ::: "memory");
        __builtin_amdgcn_sched_barrier(0);
    };
    // shfl redistribution (R7-verified): P[4 groups] -> af[2]
    auto build_af = [&](const f32x4_t P[4], bf16x8_t af[2]) {
        unsigned int w0[4], w1[4];
#pragma unroll
        for (int s = 0; s < 4; ++s) {
            w0[s] = pack2(P[s][0], P[s][1]);
            w1[s] = pack2(P[s][2], P[s][3]);
        }
#pragma unroll
        for (int k2 = 0; k2 < 2; ++k2) {
            const int sL = 2 * k2, sH = 2 * k2 + 1;
            unsigned int W0a = (unsigned int)__shfl((int)w0[sL], laneA);
            unsigned int W0b = (unsigned int)__shfl((int)w0[sH], laneA);
            unsigned int W1a = (unsigned int)__shfl((int)w1[sL], laneA);
            unsigned int W1b = (unsigned int)__shfl((int)w1[sH], laneA);
            unsigned int W2a = (unsigned int)__shfl((int)w0[sL], laneB);
            unsigned int W2b = (unsigned int)__shfl((int)w0[sH], laneB);
            unsigned int W3a = (unsigned int)__shfl((int)w1[sL], laneB);
            unsigned int W3b = (unsigned int)__shfl((int)w1[sH], laneB);
            uint4s W;
            W.x = selHi ? W0b : W0a;
            W.y = selHi ? W1b : W1a;
            W.z = selHi ? W2b : W2a;
            W.w = selHi ? W3b : W3a;
            af[k2] = __builtin_bit_cast(bf16x8_t, W);
        }
    };

    {
        bf16x8_t kreg[2], vreg[2];
        stage_load_K(0, kreg);
        stage_load_V(0, vreg);
        stage_write_K(Klds[0], kreg);
        stage_write_V(Vlds[0], vreg);
        lds_sync();
        for (int kb = 0; kb < NIT; ++kb) {
            const int kbase = kb * KBLK;
            bf16x8_t knx[2], vnx[2];
            if (kb + 1 < NIT) {
                stage_load_K(kbase + KBLK, knx);
                stage_load_V(kbase + KBLK, vnx);
            }
            const unsigned short* Kc = Klds[kb & 1];
            const unsigned short* Vc = Vlds[kb & 1];

            // QK^T both sub-tiles (swapped: D rows = keys, cols = q)
            f32x4_t A0[4], A1[4];
#pragma unroll
            for (int s = 0; s < 4; ++s) {
                bf16x8_t k0 = read_tile(Kc, s, 0), k1 = read_tile(Kc, s, 1);
                f32x4_t a0 = {0.f,0.f,0.f,0.f}, a1 = {0.f,0.f,0.f,0.f};
                a0 = __builtin_amdgcn_mfma_f32_16x16x32_bf16(k0, aq0_0, a0, 0, 0, 0);
                a0 = __builtin_amdgcn_mfma_f32_16x16x32_bf16(k1, aq1_0, a0, 0, 0, 0);
                a1 = __builtin_amdgcn_mfma_f32_16x16x32_bf16(k0, aq0_1, a1, 0, 0, 0);
                a1 = __builtin_amdgcn_mfma_f32_16x16x32_bf16(k1, aq1_1, a1, 0, 0, 0);
                A0[s] = a0; A1[s] = a1;
            }

            // softmax -> normalized p
            f32x4_t P0[4], P1[4];
#pragma unroll
            for (int s = 0; s < 4; ++s) {
#pragma unroll
                for (int r = 0; r < 4; ++r) {
                    P0[s][r] = __builtin_amdgcn_exp2f(A0[s][r] - nlg0);
                    P1[s][r] = __builtin_amdgcn_exp2f(A1[s][r] - nlg1);
                }
            }

            // PV
            bf16x8_t af0[2], af1[2];
            build_af(P0, af0);
            build_af(P1, af1);
#pragma unroll
            for (int dt = 0; dt < 4; ++dt) {
                bf16x8_t v0 = read_tile(Vc, dt, 0), v1 = read_tile(Vc, dt, 1);
                oacc0[dt] = __builtin_amdgcn_mfma_f32_16x16x32_bf16(af0[0], v0, oacc0[dt], 0, 0, 0);
                oacc0[dt] = __builtin_amdgcn_mfma_f32_16x16x32_bf16(af0[1], v1, oacc0[dt], 0, 0, 0);
                oacc1[dt] = __builtin_amdgcn_mfma_f32_16x16x32_bf16(af1[0], v0, oacc1[dt], 0, 0, 0);
                oacc1[dt] = __builtin_amdgcn_mfma_f32_16x16x32_bf16(af1[1], v1, oacc1[dt], 0, 0, 0);
            }

            // attn stores (transposed, full-line)
            store_sub(P0, 0, kbase);
            store_sub(P1, 1, kbase);

            if (kb + 1 < NIT) {
                stage_write_K(Klds[(kb + 1) & 1], knx);
                stage_write_V(Vlds[(kb + 1) & 1], vnx);
            }
            lds_sync();
        }
    }

    // --- epilogue: output (normalized)
#pragma unroll
    for (int dt = 0; dt < 4; ++dt) {
#pragma unroll
        for (int r = 0; r < 4; ++r) {
            outW[(size_t)(hi * 4 + r) * DDIM + dt * 16 + l15] = oacc0[dt][r];
            outW[(size_t)(16 + hi * 4 + r) * DDIM + dt * 16 + l15] = oacc1[dt][r];
        }
    }
}

extern "C" void kernel_launch(void* const* d_in, const int* in_sizes, int n_in,
                              void* d_out, int out_size, void* d_ws, size_t ws_size,
                              hipStream_t stream) {
    const float* Q = (const float*)d_in[0];
    const float* K = (const float*)d_in[1];
    const float* V = (const float*)d_in[2];
    float* out  = (float*)d_out;
    float* attn = out + (size_t)NBH * SDIM * DDIM;

    unsigned short* Kb = (unsigned short*)d_ws;
    unsigned short* VT = Kb + (size_t)NBH * SDIM * DDIM;

    cvt_k_kernel<<<dim3((NBH * SDIM * DDIM) / (256 * 8)), dim3(256), 0, stream>>>(K, Kb);
    tr_v_kernel<<<dim3(NBH * 32), dim3(256), 0, stream>>>(V, VT);

    sdpa_main_kernel<<<dim3(NBH * 16), dim3(256), 0, stream>>>(Q, Kb, VT, out, attn);
}

// Round 13
// 226.655 us; speedup vs baseline: 1.2791x; 1.2791x over previous
//
#include <hip/hip_runtime.h>
#include <hip/hip_bf16.h>

typedef short bf16x8_t __attribute__((ext_vector_type(8)));
typedef float f32x4_t __attribute__((ext_vector_type(4)));

#define SDIM 2048
#define DDIM 64
#define KBLK 64
#define NIT  (SDIM / KBLK)
#define NBH  48

__device__ __forceinline__ unsigned short f2bf(float f) {
    return __builtin_bit_cast(unsigned short, (__bf16)f);
}
__device__ __forceinline__ unsigned int pack2(float lo, float hi) {
    return ((unsigned int)f2bf(hi) << 16) | (unsigned int)f2bf(lo);
}
__device__ __forceinline__ bf16x8_t pack8(f32x4_t a, f32x4_t b) {
    bf16x8_t r;
    r[0] = (short)f2bf(a[0]); r[1] = (short)f2bf(a[1]);
    r[2] = (short)f2bf(a[2]); r[3] = (short)f2bf(a[3]);
    r[4] = (short)f2bf(b[0]); r[5] = (short)f2bf(b[1]);
    r[6] = (short)f2bf(b[2]); r[7] = (short)f2bf(b[3]);
    return r;
}
__device__ __forceinline__ bf16x8_t pack8s(f32x4_t a, f32x4_t b, float s) {
    bf16x8_t r;
    r[0] = (short)f2bf(a[0] * s); r[1] = (short)f2bf(a[1] * s);
    r[2] = (short)f2bf(a[2] * s); r[3] = (short)f2bf(a[3] * s);
    r[4] = (short)f2bf(b[0] * s); r[5] = (short)f2bf(b[1] * s);
    r[6] = (short)f2bf(b[2] * s); r[7] = (short)f2bf(b[3] * s);
    return r;
}
struct uint4s { unsigned int x, y, z, w; };

__device__ __forceinline__ void lds_sync() {
    asm volatile("s_waitcnt lgkmcnt(0)" ::: "memory");
    __builtin_amdgcn_s_barrier();
    asm volatile("" ::: "memory");
}

// ---------- prep 1: K fp32 -> bf16 (row-major) ----------
__global__ __launch_bounds__(256) void cvt_k_kernel(const float* __restrict__ K,
                                                    unsigned short* __restrict__ Kb) {
    size_t i = ((size_t)blockIdx.x * 256 + threadIdx.x) * 8;
    f32x4_t a = *(const f32x4_t*)(K + i);
    f32x4_t b = *(const f32x4_t*)(K + i + 4);
    *(bf16x8_t*)(Kb + i) = pack8(a, b);
}

// ---------- prep 2: V fp32 [bh][k][d] -> bf16 V^T [bh][d][k] ----------
__global__ __launch_bounds__(256) void tr_v_kernel(const float* __restrict__ V,
                                                   unsigned short* __restrict__ VT) {
    __shared__ unsigned short lt[64 * 72];
    const int bh = blockIdx.x >> 5;
    const int kt = blockIdx.x & 31;
    const float* Vb = V + (size_t)bh * (SDIM * DDIM) + (size_t)kt * 64 * DDIM;
    unsigned short* VTb = VT + (size_t)bh * (DDIM * SDIM) + kt * 64;
    const int t = threadIdx.x;
    {
        const int kl = t >> 2, dg = t & 3;
        const float* vp = Vb + kl * DDIM + dg * 16;
        f32x4_t v0 = *(const f32x4_t*)vp;
        f32x4_t v1 = *(const f32x4_t*)(vp + 4);
        f32x4_t v2 = *(const f32x4_t*)(vp + 8);
        f32x4_t v3 = *(const f32x4_t*)(vp + 12);
#pragma unroll
        for (int j = 0; j < 16; ++j) {
            float f = (j < 4) ? v0[j] : (j < 8) ? v1[j - 4] : (j < 12) ? v2[j - 8] : v3[j - 12];
            lt[(dg * 16 + j) * 72 + kl] = f2bf(f);
        }
    }
    __syncthreads();
    {
        const int d = t >> 2, kg = t & 3;
        bf16x8_t w0 = *(const bf16x8_t*)&lt[d * 72 + kg * 16];
        bf16x8_t w1 = *(const bf16x8_t*)&lt[d * 72 + kg * 16 + 8];
        *(bf16x8_t*)(VTb + (size_t)d * SDIM + kg * 16) = w0;
        *(bf16x8_t*)(VTb + (size_t)d * SDIM + kg * 16 + 8) = w1;
    }
}

// ---------- main: chunk-pipelined (passA(c1) fused under passB(c0) stores) ----------
__global__ __launch_bounds__(256, 2) void sdpa_main_kernel(
    const float* __restrict__ Q, const unsigned short* __restrict__ Kb,
    const unsigned short* __restrict__ VT, float* __restrict__ out,
    float* __restrict__ attn)
{
    __shared__ __align__(16) unsigned short Klds[2][KBLK * DDIM];  // 2 x 8KB
    __shared__ __align__(16) unsigned short Vlds[2][KBLK * DDIM];  // 2 x 8KB
    __shared__ __align__(16) float pbuf[4][16 * 64];               // 16KB

    const int bid = blockIdx.x;
    const int bh  = bid >> 4;      // R11 mapping (R12's XCD swizzle regressed -> reverted)
    const int qt  = bid & 15;
    const int tid = threadIdx.x;
    const int lane = tid & 63;
    const int wv   = tid >> 6;     // 0..3
    const int l15  = lane & 15;
    const int hi   = lane >> 4;    // 0..3
    const int qbase = qt * 128 + wv * 32;

    const unsigned short* KbB = Kb + (size_t)bh * (SDIM * DDIM);
    const unsigned short* VTb = VT + (size_t)bh * (DDIM * SDIM);
    float* outW  = out  + ((size_t)bh * SDIM + qbase) * DDIM;
    float* attnW = attn + (size_t)bh * SDIM * SDIM + (size_t)qbase * SDIM;
    float* pb = pbuf[wv];

    const float SC = 0.18033688011112042f;  // (1/sqrt(64)) * log2(e)

    // ---- Q fragments (B operand), 2 sub-tiles, pre-scaled by SC
    const float* qp0 = Q + ((size_t)bh * SDIM + qbase + l15) * DDIM + hi * 8;
    const float* qp1 = qp0 + (size_t)16 * DDIM;
    const bf16x8_t aq0_0 = pack8s(*(const f32x4_t*)qp0,        *(const f32x4_t*)(qp0 + 4), SC);
    const bf16x8_t aq1_0 = pack8s(*(const f32x4_t*)(qp0 + 32), *(const f32x4_t*)(qp0 + 36), SC);
    const bf16x8_t aq0_1 = pack8s(*(const f32x4_t*)qp1,        *(const f32x4_t*)(qp1 + 4), SC);
    const bf16x8_t aq1_1 = pack8s(*(const f32x4_t*)(qp1 + 32), *(const f32x4_t*)(qp1 + 36), SC);

    // ---- staging helpers (contiguous full-line global access; 256 threads)
    auto stage_load_K = [&](int kbase, bf16x8_t kreg[2]) {
#pragma unroll
        for (int j = 0; j < 2; ++j)
            kreg[j] = *(const bf16x8_t*)(KbB + (size_t)kbase * DDIM + (j * 256 + tid) * 8);
    };
    auto stage_write_K = [&](unsigned short* dst, const bf16x8_t kreg[2]) {
#pragma unroll
        for (int j = 0; j < 2; ++j) {
            const int b = (j * 256 + tid) * 16;
            const int row = b >> 7;
            *(bf16x8_t*)((char*)dst + (b ^ ((row & 7) << 4))) = kreg[j];
        }
    };
    auto stage_load_V = [&](int kbase, bf16x8_t vreg[2]) {
#pragma unroll
        for (int j = 0; j < 2; ++j) {
            const int row = j * 32 + (tid >> 3);
            vreg[j] = *(const bf16x8_t*)(VTb + (size_t)row * SDIM + kbase + (tid & 7) * 8);
        }
    };
    auto stage_write_V = [&](unsigned short* dst, const bf16x8_t vreg[2]) {
#pragma unroll
        for (int j = 0; j < 2; ++j) {
            const int row = j * 32 + (tid >> 3);
            const int b = row * 128 + (tid & 7) * 16;
            *(bf16x8_t*)((char*)dst + (b ^ ((row & 7) << 4))) = vreg[j];
        }
    };
    auto read_tile = [&](const unsigned short* src, int s, int c) -> bf16x8_t {
        const int row = s * 16 + l15;
        const int b = row * 128 + c * 64 + hi * 16;
        return *(const bf16x8_t*)((const char*)src + (b ^ ((row & 7) << 4)));
    };

    const int laneA = l15 + ((hi & 1) << 5);
    const int laneB = laneA + 16;
    const bool selHi = (hi >> 1) != 0;

    // p transpose-store through pbuf: full-line global writes (R10-verified)
    auto store_sub = [&](const f32x4_t P[4], int t, int kbase) {
#pragma unroll
        for (int g = 0; g < 4; ++g) {
            const int c4 = (g * 4 + hi) ^ ((l15 & 7) << 1);
            *(f32x4_t*)(pb + l15 * 64 + c4 * 4) = P[g];
        }
        asm volatile("s_waitcnt lgkmcnt(0)" ::: "memory");
        __builtin_amdgcn_sched_barrier(0);
#pragma unroll
        for (int j = 0; j < 4; ++j) {
            const int row = j * 4 + (lane & 3);
            const int c4 = lane >> 2;
            f32x4_t v = *(const f32x4_t*)(pb + row * 64 + (c4 ^ ((row & 7) << 1)) * 4);
            __builtin_nontemporal_store(v,
                (f32x4_t*)(attnW + (size_t)(t * 16 + row) * SDIM + kbase + c4 * 4));
        }
        asm volatile("s_waitcnt lgkmcnt(0)" ::: "memory");
        __builtin_amdgcn_sched_barrier(0);
    };
    // shfl redistribution (R7-verified): P[4 groups] -> af[2]
    auto build_af = [&](const f32x4_t P[4], bf16x8_t af[2]) {
        unsigned int w0[4], w1[4];
#pragma unroll
        for (int s = 0; s < 4; ++s) {
            w0[s] = pack2(P[s][0], P[s][1]);
            w1[s] = pack2(P[s][2], P[s][3]);
        }
#pragma unroll
        for (int k2 = 0; k2 < 2; ++k2) {
            const int sL = 2 * k2, sH = 2 * k2 + 1;
            unsigned int W0a = (unsigned int)__shfl((int)w0[sL], laneA);
            unsigned int W0b = (unsigned int)__shfl((int)w0[sH], laneA);
            unsigned int W1a = (unsigned int)__shfl((int)w1[sL], laneA);
            unsigned int W1b = (unsigned int)__shfl((int)w1[sH], laneA);
            unsigned int W2a = (unsigned int)__shfl((int)w0[sL], laneB);
            unsigned int W2b = (unsigned int)__shfl((int)w0[sH], laneB);
            unsigned int W3a = (unsigned int)__shfl((int)w1[sL], laneB);
            unsigned int W3b = (unsigned int)__shfl((int)w1[sH], laneB);
            uint4s W;
            W.x = selHi ? W0b : W0a;
            W.y = selHi ? W1b : W1a;
            W.z = selHi ? W2b : W2a;
            W.w = selHi ? W3b : W3a;
            af[k2] = __builtin_bit_cast(bf16x8_t, W);
        }
    };

    // ============ phase 1: pass A for chunk 0 only (half-size serial prefix) ============
    float rs0 = 0.f;
    {
        bf16x8_t kreg[2];
        stage_load_K(0, kreg);
        stage_write_K(Klds[0], kreg);
        lds_sync();
        for (int kb = 0; kb < NIT; ++kb) {
            bf16x8_t knx[2];
            if (kb + 1 < NIT) stage_load_K((kb + 1) * KBLK, knx);
            const unsigned short* Kc = Klds[kb & 1];
#pragma unroll
            for (int s = 0; s < 4; ++s) {
                bf16x8_t k0 = read_tile(Kc, s, 0), k1 = read_tile(Kc, s, 1);
                f32x4_t a0 = {0.f,0.f,0.f,0.f};
                a0 = __builtin_amdgcn_mfma_f32_16x16x32_bf16(k0, aq0_0, a0, 0, 0, 0);
                a0 = __builtin_amdgcn_mfma_f32_16x16x32_bf16(k1, aq1_0, a0, 0, 0, 0);
                rs0 += __builtin_amdgcn_exp2f(a0[0]) + __builtin_amdgcn_exp2f(a0[1])
                     + __builtin_amdgcn_exp2f(a0[2]) + __builtin_amdgcn_exp2f(a0[3]);
            }
            if (kb + 1 < NIT) stage_write_K(Klds[(kb + 1) & 1], knx);
            lds_sync();
        }
    }
    rs0 += __shfl_xor(rs0, 16); rs0 += __shfl_xor(rs0, 32);
    const float nlg0 = __builtin_amdgcn_logf(rs0);

    // ============ phase 2: pass B (chunk 0) fused with pass A (chunk 1) ============
    f32x4_t oacc0[4] = {{0.f,0.f,0.f,0.f},{0.f,0.f,0.f,0.f},{0.f,0.f,0.f,0.f},{0.f,0.f,0.f,0.f}};
    float rs1 = 0.f;
    {
        bf16x8_t kreg[2], vreg[2];
        stage_load_K(0, kreg);
        stage_load_V(0, vreg);
        stage_write_K(Klds[0], kreg);
        stage_write_V(Vlds[0], vreg);
        lds_sync();
        for (int kb = 0; kb < NIT; ++kb) {
            const int kbase = kb * KBLK;
            bf16x8_t knx[2], vnx[2];
            if (kb + 1 < NIT) {
                stage_load_K(kbase + KBLK, knx);
                stage_load_V(kbase + KBLK, vnx);
            }
            const unsigned short* Kc = Klds[kb & 1];
            const unsigned short* Vc = Vlds[kb & 1];

            // QK^T chunk0 (kept) + chunk1 (row-sum only), same staged K tile
            f32x4_t A0[4];
#pragma unroll
            for (int s = 0; s < 4; ++s) {
                bf16x8_t k0 = read_tile(Kc, s, 0), k1 = read_tile(Kc, s, 1);
                f32x4_t a0 = {0.f,0.f,0.f,0.f}, a1 = {0.f,0.f,0.f,0.f};
                a0 = __builtin_amdgcn_mfma_f32_16x16x32_bf16(k0, aq0_0, a0, 0, 0, 0);
                a0 = __builtin_amdgcn_mfma_f32_16x16x32_bf16(k1, aq1_0, a0, 0, 0, 0);
                a1 = __builtin_amdgcn_mfma_f32_16x16x32_bf16(k0, aq0_1, a1, 0, 0, 0);
                a1 = __builtin_amdgcn_mfma_f32_16x16x32_bf16(k1, aq1_1, a1, 0, 0, 0);
                A0[s] = a0;
                rs1 += __builtin_amdgcn_exp2f(a1[0]) + __builtin_amdgcn_exp2f(a1[1])
                     + __builtin_amdgcn_exp2f(a1[2]) + __builtin_amdgcn_exp2f(a1[3]);
            }

            f32x4_t P0[4];
#pragma unroll
            for (int s = 0; s < 4; ++s) {
#pragma unroll
                for (int r = 0; r < 4; ++r)
                    P0[s][r] = __builtin_amdgcn_exp2f(A0[s][r] - nlg0);
            }

            bf16x8_t af0[2];
            build_af(P0, af0);
#pragma unroll
            for (int dt = 0; dt < 4; ++dt) {
                bf16x8_t v0 = read_tile(Vc, dt, 0), v1 = read_tile(Vc, dt, 1);
                oacc0[dt] = __builtin_amdgcn_mfma_f32_16x16x32_bf16(af0[0], v0, oacc0[dt], 0, 0, 0);
                oacc0[dt] = __builtin_amdgcn_mfma_f32_16x16x32_bf16(af0[1], v1, oacc0[dt], 0, 0, 0);
            }

            store_sub(P0, 0, kbase);

            if (kb + 1 < NIT) {
                stage_write_K(Klds[(kb + 1) & 1], knx);
                stage_write_V(Vlds[(kb + 1) & 1], vnx);
            }
            lds_sync();
        }
    }
    rs1 += __shfl_xor(rs1, 16); rs1 += __shfl_xor(rs1, 32);
    const float nlg1 = __builtin_amdgcn_logf(rs1);

    // ============ phase 3: pass B (chunk 1) ============
    f32x4_t oacc1[4] = {{0.f,0.f,0.f,0.f},{0.f,0.f,0.f,0.f},{0.f,0.f,0.f,0.f},{0.f,0.f,0.f,0.f}};
    {
        bf16x8_t kreg[2], vreg[2];
        stage_load_K(0, kreg);
        stage_load_V(0, vreg);
        stage_write_K(Klds[0], kreg);
        stage_write_V(Vlds[0], vreg);
        lds_sync();
        for (int kb = 0; kb < NIT; ++kb) {
            const int kbase = kb * KBLK;
            bf16x8_t knx[2], vnx[2];
            if (kb + 1 < NIT) {
                stage_load_K(kbase + KBLK, knx);
                stage_load_V(kbase + KBLK, vnx);
            }
            const unsigned short* Kc = Klds[kb & 1];
            const unsigned short* Vc = Vlds[kb & 1];

            f32x4_t A1[4];
#pragma unroll
            for (int s = 0; s < 4; ++s) {
                bf16x8_t k0 = read_tile(Kc, s, 0), k1 = read_tile(Kc, s, 1);
                f32x4_t a1 = {0.f,0.f,0.f,0.f};
                a1 = __builtin_amdgcn_mfma_f32_16x16x32_bf16(k0, aq0_1, a1, 0, 0, 0);
                a1 = __builtin_amdgcn_mfma_f32_16x16x32_bf16(k1, aq1_1, a1, 0, 0, 0);
                A1[s] = a1;
            }

            f32x4_t P1[4];
#pragma unroll
            for (int s = 0; s < 4; ++s) {
#pragma unroll
                for (int r = 0; r < 4; ++r)
                    P1[s][r] = __builtin_amdgcn_exp2f(A1[s][r] - nlg1);
            }

            bf16x8_t af1[2];
            build_af(P1, af1);
#pragma unroll
            for (int dt = 0; dt < 4; ++dt) {
                bf16x8_t v0 = read_tile(Vc, dt, 0), v1 = read_tile(Vc, dt, 1);
                oacc1[dt] = __builtin_amdgcn_mfma_f32_16x16x32_bf16(af1[0], v0, oacc1[dt], 0, 0, 0);
                oacc1[dt] = __builtin_amdgcn_mfma_f32_16x16x32_bf16(af1[1], v1, oacc1[dt], 0, 0, 0);
            }

            store_sub(P1, 1, kbase);

            if (kb + 1 < NIT) {
                stage_write_K(Klds[(kb + 1) & 1], knx);
                stage_write_V(Vlds[(kb + 1) & 1], vnx);
            }
            lds_sync();
        }
    }

    // --- epilogue: output (normalized)
#pragma unroll
    for (int dt = 0; dt < 4; ++dt) {
#pragma unroll
        for (int r = 0; r < 4; ++r) {
            outW[(size_t)(hi * 4 + r) * DDIM + dt * 16 + l15] = oacc0[dt][r];
            outW[(size_t)(16 + hi * 4 + r) * DDIM + dt * 16 + l15] = oacc1[dt][r];
        }
    }
}

extern "C" void kernel_launch(void* const* d_in, const int* in_sizes, int n_in,
                              void* d_out, int out_size, void* d_ws, size_t ws_size,
                              hipStream_t stream) {
    const float* Q = (const float*)d_in[0];
    const float* K = (const float*)d_in[1];
    const float* V = (const float*)d_in[2];
    float* out  = (float*)d_out;
    float* attn = out + (size_t)NBH * SDIM * DDIM;

    unsigned short* Kb = (unsigned short*)d_ws;
    unsigned short* VT = Kb + (size_t)NBH * SDIM * DDIM;

    cvt_k_kernel<<<dim3((NBH * SDIM * DDIM) / (256 * 8)), dim3(256), 0, stream>>>(K, Kb);
    tr_v_kernel<<<dim3(NBH * 32), dim3(256), 0, stream>>>(V, VT);

    sdpa_main_kernel<<<dim3(NBH * 16), dim3(256), 0, stream>>>(Q, Kb, VT, out, attn);
}

// Round 14
// 224.727 us; speedup vs baseline: 1.2901x; 1.0086x over previous
//
#include <hip/hip_runtime.h>
#include <hip/hip_bf16.h>

typedef short bf16x8_t __attribute__((ext_vector_type(8)));
typedef float f32x4_t __attribute__((ext_vector_type(4)));

#define SDIM 2048
#define DDIM 64
#define KBLK 64
#define NIT  (SDIM / KBLK)
#define NBH  48

__device__ __forceinline__ unsigned short f2bf(float f) {
    return __builtin_bit_cast(unsigned short, (__bf16)f);
}
__device__ __forceinline__ unsigned int pack2(float lo, float hi) {
    return ((unsigned int)f2bf(hi) << 16) | (unsigned int)f2bf(lo);
}
__device__ __forceinline__ bf16x8_t pack8(f32x4_t a, f32x4_t b) {
    bf16x8_t r;
    r[0] = (short)f2bf(a[0]); r[1] = (short)f2bf(a[1]);
    r[2] = (short)f2bf(a[2]); r[3] = (short)f2bf(a[3]);
    r[4] = (short)f2bf(b[0]); r[5] = (short)f2bf(b[1]);
    r[6] = (short)f2bf(b[2]); r[7] = (short)f2bf(b[3]);
    return r;
}
__device__ __forceinline__ bf16x8_t pack8s(f32x4_t a, f32x4_t b, float s) {
    bf16x8_t r;
    r[0] = (short)f2bf(a[0] * s); r[1] = (short)f2bf(a[1] * s);
    r[2] = (short)f2bf(a[2] * s); r[3] = (short)f2bf(a[3] * s);
    r[4] = (short)f2bf(b[0] * s); r[5] = (short)f2bf(b[1] * s);
    r[6] = (short)f2bf(b[2] * s); r[7] = (short)f2bf(b[3] * s);
    return r;
}
struct uint4s { unsigned int x, y, z, w; };

__device__ __forceinline__ void lds_sync() {
    asm volatile("s_waitcnt lgkmcnt(0)" ::: "memory");
    __builtin_amdgcn_s_barrier();
    asm volatile("" ::: "memory");
}

// ---------- prep 1: K fp32 -> bf16 (row-major) ----------
__global__ __launch_bounds__(256) void cvt_k_kernel(const float* __restrict__ K,
                                                    unsigned short* __restrict__ Kb) {
    size_t i = ((size_t)blockIdx.x * 256 + threadIdx.x) * 8;
    f32x4_t a = *(const f32x4_t*)(K + i);
    f32x4_t b = *(const f32x4_t*)(K + i + 4);
    *(bf16x8_t*)(Kb + i) = pack8(a, b);
}

// ---------- prep 2: V fp32 [bh][k][d] -> bf16 V^T [bh][d][k] ----------
__global__ __launch_bounds__(256) void tr_v_kernel(const float* __restrict__ V,
                                                   unsigned short* __restrict__ VT) {
    __shared__ unsigned short lt[64 * 72];
    const int bh = blockIdx.x >> 5;
    const int kt = blockIdx.x & 31;
    const float* Vb = V + (size_t)bh * (SDIM * DDIM) + (size_t)kt * 64 * DDIM;
    unsigned short* VTb = VT + (size_t)bh * (DDIM * SDIM) + kt * 64;
    const int t = threadIdx.x;
    {
        const int kl = t >> 2, dg = t & 3;
        const float* vp = Vb + kl * DDIM + dg * 16;
        f32x4_t v0 = *(const f32x4_t*)vp;
        f32x4_t v1 = *(const f32x4_t*)(vp + 4);
        f32x4_t v2 = *(const f32x4_t*)(vp + 8);
        f32x4_t v3 = *(const f32x4_t*)(vp + 12);
#pragma unroll
        for (int j = 0; j < 16; ++j) {
            float f = (j < 4) ? v0[j] : (j < 8) ? v1[j - 4] : (j < 12) ? v2[j - 8] : v3[j - 12];
            lt[(dg * 16 + j) * 72 + kl] = f2bf(f);
        }
    }
    __syncthreads();
    {
        const int d = t >> 2, kg = t & 3;
        bf16x8_t w0 = *(const bf16x8_t*)&lt[d * 72 + kg * 16];
        bf16x8_t w1 = *(const bf16x8_t*)&lt[d * 72 + kg * 16 + 8];
        *(bf16x8_t*)(VTb + (size_t)d * SDIM + kg * 16) = w0;
        *(bf16x8_t*)(VTb + (size_t)d * SDIM + kg * 16 + 8) = w1;
    }
}

// ---------- main: chunk-pipelined (passA(c1) fused under passB(c0) stores) ----------
__global__ __launch_bounds__(256, 2) void sdpa_main_kernel(
    const float* __restrict__ Q, const unsigned short* __restrict__ Kb,
    const unsigned short* __restrict__ VT, float* __restrict__ out,
    float* __restrict__ attn)
{
    __shared__ __align__(16) unsigned short Klds[2][KBLK * DDIM];  // 2 x 8KB
    __shared__ __align__(16) unsigned short Vlds[2][KBLK * DDIM];  // 2 x 8KB
    __shared__ __align__(16) float pbuf[4][16 * 64];               // 16KB

    const int bid = blockIdx.x;
    const int bh  = bid >> 4;      // R11 mapping (R12's XCD swizzle regressed -> reverted)
    const int qt  = bid & 15;
    const int tid = threadIdx.x;
    const int lane = tid & 63;
    const int wv   = tid >> 6;     // 0..3
    const int l15  = lane & 15;
    const int hi   = lane >> 4;    // 0..3
    const int qbase = qt * 128 + wv * 32;

    const unsigned short* KbB = Kb + (size_t)bh * (SDIM * DDIM);
    const unsigned short* VTb = VT + (size_t)bh * (DDIM * SDIM);
    float* outW  = out  + ((size_t)bh * SDIM + qbase) * DDIM;
    float* attnW = attn + (size_t)bh * SDIM * SDIM + (size_t)qbase * SDIM;
    float* pb = pbuf[wv];

    const float SC = 0.18033688011112042f;  // (1/sqrt(64)) * log2(e)

    // ---- Q fragments (B operand), 2 sub-tiles, pre-scaled by SC
    const float* qp0 = Q + ((size_t)bh * SDIM + qbase + l15) * DDIM + hi * 8;
    const float* qp1 = qp0 + (size_t)16 * DDIM;
    const bf16x8_t aq0_0 = pack8s(*(const f32x4_t*)qp0,        *(const f32x4_t*)(qp0 + 4), SC);
    const bf16x8_t aq1_0 = pack8s(*(const f32x4_t*)(qp0 + 32), *(const f32x4_t*)(qp0 + 36), SC);
    const bf16x8_t aq0_1 = pack8s(*(const f32x4_t*)qp1,        *(const f32x4_t*)(qp1 + 4), SC);
    const bf16x8_t aq1_1 = pack8s(*(const f32x4_t*)(qp1 + 32), *(const f32x4_t*)(qp1 + 36), SC);

    // ---- staging helpers (contiguous full-line global access; 256 threads)
    auto stage_load_K = [&](int kbase, bf16x8_t kreg[2]) {
#pragma unroll
        for (int j = 0; j < 2; ++j)
            kreg[j] = *(const bf16x8_t*)(KbB + (size_t)kbase * DDIM + (j * 256 + tid) * 8);
    };
    auto stage_write_K = [&](unsigned short* dst, const bf16x8_t kreg[2]) {
#pragma unroll
        for (int j = 0; j < 2; ++j) {
            const int b = (j * 256 + tid) * 16;
            const int row = b >> 7;
            *(bf16x8_t*)((char*)dst + (b ^ ((row & 7) << 4))) = kreg[j];
        }
    };
    auto stage_load_V = [&](int kbase, bf16x8_t vreg[2]) {
#pragma unroll
        for (int j = 0; j < 2; ++j) {
            const int row = j * 32 + (tid >> 3);
            vreg[j] = *(const bf16x8_t*)(VTb + (size_t)row * SDIM + kbase + (tid & 7) * 8);
        }
    };
    auto stage_write_V = [&](unsigned short* dst, const bf16x8_t vreg[2]) {
#pragma unroll
        for (int j = 0; j < 2; ++j) {
            const int row = j * 32 + (tid >> 3);
            const int b = row * 128 + (tid & 7) * 16;
            *(bf16x8_t*)((char*)dst + (b ^ ((row & 7) << 4))) = vreg[j];
        }
    };
    auto read_tile = [&](const unsigned short* src, int s, int c) -> bf16x8_t {
        const int row = s * 16 + l15;
        const int b = row * 128 + c * 64 + hi * 16;
        return *(const bf16x8_t*)((const char*)src + (b ^ ((row & 7) << 4)));
    };

    const int laneA = l15 + ((hi & 1) << 5);
    const int laneB = laneA + 16;
    const bool selHi = (hi >> 1) != 0;

    // p transpose-store through pbuf: full-line global writes (R10-verified)
    auto store_sub = [&](const f32x4_t P[4], int t, int kbase) {
#pragma unroll
        for (int g = 0; g < 4; ++g) {
            const int c4 = (g * 4 + hi) ^ ((l15 & 7) << 1);
            *(f32x4_t*)(pb + l15 * 64 + c4 * 4) = P[g];
        }
        asm volatile("s_waitcnt lgkmcnt(0)" ::: "memory");
        __builtin_amdgcn_sched_barrier(0);
#pragma unroll
        for (int j = 0; j < 4; ++j) {
            const int row = j * 4 + (lane & 3);
            const int c4 = lane >> 2;
            f32x4_t v = *(const f32x4_t*)(pb + row * 64 + (c4 ^ ((row & 7) << 1)) * 4);
            __builtin_nontemporal_store(v,
                (f32x4_t*)(attnW + (size_t)(t * 16 + row) * SDIM + kbase + c4 * 4));
        }
        asm volatile("s_waitcnt lgkmcnt(0)" ::: "memory");
        __builtin_amdgcn_sched_barrier(0);
    };
    // shfl redistribution (R7-verified): P[4 groups] -> af[2]
    auto build_af = [&](const f32x4_t P[4], bf16x8_t af[2]) {
        unsigned int w0[4], w1[4];
#pragma unroll
        for (int s = 0; s < 4; ++s) {
            w0[s] = pack2(P[s][0], P[s][1]);
            w1[s] = pack2(P[s][2], P[s][3]);
        }
#pragma unroll
        for (int k2 = 0; k2 < 2; ++k2) {
            const int sL = 2 * k2, sH = 2 * k2 + 1;
            unsigned int W0a = (unsigned int)__shfl((int)w0[sL], laneA);
            unsigned int W0b = (unsigned int)__shfl((int)w0[sH], laneA);
            unsigned int W1a = (unsigned int)__shfl((int)w1[sL], laneA);
            unsigned int W1b = (unsigned int)__shfl((int)w1[sH], laneA);
            unsigned int W2a = (unsigned int)__shfl((int)w0[sL], laneB);
            unsigned int W2b = (unsigned int)__shfl((int)w0[sH], laneB);
            unsigned int W3a = (unsigned int)__shfl((int)w1[sL], laneB);
            unsigned int W3b = (unsigned int)__shfl((int)w1[sH], laneB);
            uint4s W;
            W.x = selHi ? W0b : W0a;
            W.y = selHi ? W1b : W1a;
            W.z = selHi ? W2b : W2a;
            W.w = selHi ? W3b : W3a;
            af[k2] = __builtin_bit_cast(bf16x8_t, W);
        }
    };

    // ============ phase 1: pass A for chunk 0 only (half-size serial prefix) ============
    float rs0 = 0.f;
    {
        bf16x8_t kreg[2];
        stage_load_K(0, kreg);
        stage_write_K(Klds[0], kreg);
        lds_sync();
        for (int kb = 0; kb < NIT; ++kb) {
            bf16x8_t knx[2];
            if (kb + 1 < NIT) stage_load_K((kb + 1) * KBLK, knx);
            const unsigned short* Kc = Klds[kb & 1];
#pragma unroll
            for (int s = 0; s < 4; ++s) {
                bf16x8_t k0 = read_tile(Kc, s, 0), k1 = read_tile(Kc, s, 1);
                f32x4_t a0 = {0.f,0.f,0.f,0.f};
                a0 = __builtin_amdgcn_mfma_f32_16x16x32_bf16(k0, aq0_0, a0, 0, 0, 0);
                a0 = __builtin_amdgcn_mfma_f32_16x16x32_bf16(k1, aq1_0, a0, 0, 0, 0);
                rs0 += __builtin_amdgcn_exp2f(a0[0]) + __builtin_amdgcn_exp2f(a0[1])
                     + __builtin_amdgcn_exp2f(a0[2]) + __builtin_amdgcn_exp2f(a0[3]);
            }
            if (kb + 1 < NIT) stage_write_K(Klds[(kb + 1) & 1], knx);
            lds_sync();
        }
    }
    rs0 += __shfl_xor(rs0, 16); rs0 += __shfl_xor(rs0, 32);
    const float nlg0 = __builtin_amdgcn_logf(rs0);

    // ============ phase 2: pass B (chunk 0) fused with pass A (chunk 1) ============
    f32x4_t oacc0[4] = {{0.f,0.f,0.f,0.f},{0.f,0.f,0.f,0.f},{0.f,0.f,0.f,0.f},{0.f,0.f,0.f,0.f}};
    float rs1 = 0.f;
    {
        bf16x8_t kreg[2], vreg[2];
        stage_load_K(0, kreg);
        stage_load_V(0, vreg);
        stage_write_K(Klds[0], kreg);
        stage_write_V(Vlds[0], vreg);
        lds_sync();
        for (int kb = 0; kb < NIT; ++kb) {
            const int kbase = kb * KBLK;
            bf16x8_t knx[2], vnx[2];
            if (kb + 1 < NIT) {
                stage_load_K(kbase + KBLK, knx);
                stage_load_V(kbase + KBLK, vnx);
            }
            const unsigned short* Kc = Klds[kb & 1];
            const unsigned short* Vc = Vlds[kb & 1];

            // QK^T chunk0 (kept) + chunk1 (row-sum only), same staged K tile
            f32x4_t A0[4];
#pragma unroll
            for (int s = 0; s < 4; ++s) {
                bf16x8_t k0 = read_tile(Kc, s, 0), k1 = read_tile(Kc, s, 1);
                f32x4_t a0 = {0.f,0.f,0.f,0.f}, a1 = {0.f,0.f,0.f,0.f};
                a0 = __builtin_amdgcn_mfma_f32_16x16x32_bf16(k0, aq0_0, a0, 0, 0, 0);
                a0 = __builtin_amdgcn_mfma_f32_16x16x32_bf16(k1, aq1_0, a0, 0, 0, 0);
                a1 = __builtin_amdgcn_mfma_f32_16x16x32_bf16(k0, aq0_1, a1, 0, 0, 0);
                a1 = __builtin_amdgcn_mfma_f32_16x16x32_bf16(k1, aq1_1, a1, 0, 0, 0);
                A0[s] = a0;
                rs1 += __builtin_amdgcn_exp2f(a1[0]) + __builtin_amdgcn_exp2f(a1[1])
                     + __builtin_amdgcn_exp2f(a1[2]) + __builtin_amdgcn_exp2f(a1[3]);
            }

            f32x4_t P0[4];
#pragma unroll
            for (int s = 0; s < 4; ++s) {
#pragma unroll
                for (int r = 0; r < 4; ++r)
                    P0[s][r] = __builtin_amdgcn_exp2f(A0[s][r] - nlg0);
            }

            bf16x8_t af0[2];
            build_af(P0, af0);
#pragma unroll
            for (int dt = 0; dt < 4; ++dt) {
                bf16x8_t v0 = read_tile(Vc, dt, 0), v1 = read_tile(Vc, dt, 1);
                oacc0[dt] = __builtin_amdgcn_mfma_f32_16x16x32_bf16(af0[0], v0, oacc0[dt], 0, 0, 0);
                oacc0[dt] = __builtin_amdgcn_mfma_f32_16x16x32_bf16(af0[1], v1, oacc0[dt], 0, 0, 0);
            }

            store_sub(P0, 0, kbase);

            if (kb + 1 < NIT) {
                stage_write_K(Klds[(kb + 1) & 1], knx);
                stage_write_V(Vlds[(kb + 1) & 1], vnx);
            }
            lds_sync();
        }
    }
    rs1 += __shfl_xor(rs1, 16); rs1 += __shfl_xor(rs1, 32);
    const float nlg1 = __builtin_amdgcn_logf(rs1);

    // ============ phase 3: pass B (chunk 1) ============
    f32x4_t oacc1[4] = {{0.f,0.f,0.f,0.f},{0.f,0.f,0.f,0.f},{0.f,0.f,0.f,0.f},{0.f,0.f,0.f,0.f}};
    {
        bf16x8_t kreg[2], vreg[2];
        stage_load_K(0, kreg);
        stage_load_V(0, vreg);
        stage_write_K(Klds[0], kreg);
        stage_write_V(Vlds[0], vreg);
        lds_sync();
        for (int kb = 0; kb < NIT; ++kb) {
            const int kbase = kb * KBLK;
            bf16x8_t knx[2], vnx[2];
            if (kb + 1 < NIT) {
                stage_load_K(kbase + KBLK, knx);
                stage_load_V(kbase + KBLK, vnx);
            }
            const unsigned short* Kc = Klds[kb & 1];
            const unsigned short* Vc = Vlds[kb & 1];

            f32x4_t A1[4];
#pragma unroll
            for (int s = 0; s < 4; ++s) {
                bf16x8_t k0 = read_tile(Kc, s, 0), k1 = read_tile(Kc, s, 1);
                f32x4_t a1 = {0.f,0.f,0.f,0.f};
                a1 = __builtin_amdgcn_mfma_f32_16x16x32_bf16(k0, aq0_1, a1, 0, 0, 0);
                a1 = __builtin_amdgcn_mfma_f32_16x16x32_bf16(k1, aq1_1, a1, 0, 0, 0);
                A1[s] = a1;
            }

            f32x4_t P1[4];
#pragma unroll
            for (int s = 0; s < 4; ++s) {
#pragma unroll
                for (int r = 0; r < 4; ++r)
                    P1[s][r] = __builtin_amdgcn_exp2f(A1[s][r] - nlg1);
            }

            bf16x8_t af1[2];
            build_af(P1, af1);
#pragma unroll
            for (int dt = 0; dt < 4; ++dt) {
                bf16x8_t v0 = read_tile(Vc, dt, 0), v1 = read_tile(Vc, dt, 1);
                oacc1[dt] = __builtin_amdgcn_mfma_f32_16x16x32_bf16(af1[0], v0, oacc1[dt], 0, 0, 0);
                oacc1[dt] = __builtin_amdgcn_mfma_f32_16x16x32_bf16(af1[1], v1, oacc1[dt], 0, 0, 0);
            }

            store_sub(P1, 1, kbase);

            if (kb + 1 < NIT) {
                stage_write_K(Klds[(kb + 1) & 1], knx);
                stage_write_V(Vlds[(kb + 1) & 1], vnx);
            }
            lds_sync();
        }
    }

    // --- epilogue: output (normalized)
#pragma unroll
    for (int dt = 0; dt < 4; ++dt) {
#pragma unroll
        for (int r = 0; r < 4; ++r) {
            outW[(size_t)(hi * 4 + r) * DDIM + dt * 16 + l15] = oacc0[dt][r];
            outW[(size_t)(16 + hi * 4 + r) * DDIM + dt * 16 + l15] = oacc1[dt][r];
        }
    }
}

extern "C" void kernel_launch(void* const* d_in, const int* in_sizes, int n_in,
                              void* d_out, int out_size, void* d_ws, size_t ws_size,
                              hipStream_t stream) {
    const float* Q = (const float*)d_in[0];
    const float* K = (const float*)d_in[1];
    const float* V = (const float*)d_in[2];
    float* out  = (float*)d_out;
    float* attn = out + (size_t)NBH * SDIM * DDIM;

    unsigned short* Kb = (unsigned short*)d_ws;
    unsigned short* VT = Kb + (size_t)NBH * SDIM * DDIM;

    cvt_k_kernel<<<dim3((NBH * SDIM * DDIM) / (256 * 8)), dim3(256), 0, stream>>>(K, Kb);
    tr_v_kernel<<<dim3(NBH * 32), dim3(256), 0, stream>>>(V, VT);

    sdpa_main_kernel<<<dim3(NBH * 16), dim3(256), 0, stream>>>(Q, Kb, VT, out, attn);
}

// Round 15
// 223.993 us; speedup vs baseline: 1.2943x; 1.0033x over previous
//
#include <hip/hip_runtime.h>
#include <hip/hip_bf16.h>

typedef short bf16x8_t __attribute__((ext_vector_type(8)));
typedef float f32x4_t __attribute__((ext_vector_type(4)));

#define SDIM 2048
#define DDIM 64
#define KBLK 64
#define NIT  (SDIM / KBLK)
#define NBH  48

__device__ __forceinline__ unsigned short f2bf(float f) {
    return __builtin_bit_cast(unsigned short, (__bf16)f);
}
__device__ __forceinline__ unsigned int pack2(float lo, float hi) {
    return ((unsigned int)f2bf(hi) << 16) | (unsigned int)f2bf(lo);
}
__device__ __forceinline__ bf16x8_t pack8(f32x4_t a, f32x4_t b) {
    bf16x8_t r;
    r[0] = (short)f2bf(a[0]); r[1] = (short)f2bf(a[1]);
    r[2] = (short)f2bf(a[2]); r[3] = (short)f2bf(a[3]);
    r[4] = (short)f2bf(b[0]); r[5] = (short)f2bf(b[1]);
    r[6] = (short)f2bf(b[2]); r[7] = (short)f2bf(b[3]);
    return r;
}
__device__ __forceinline__ bf16x8_t pack8s(f32x4_t a, f32x4_t b, float s) {
    bf16x8_t r;
    r[0] = (short)f2bf(a[0] * s); r[1] = (short)f2bf(a[1] * s);
    r[2] = (short)f2bf(a[2] * s); r[3] = (short)f2bf(a[3] * s);
    r[4] = (short)f2bf(b[0] * s); r[5] = (short)f2bf(b[1] * s);
    r[6] = (short)f2bf(b[2] * s); r[7] = (short)f2bf(b[3] * s);
    return r;
}
struct uint4s { unsigned int x, y, z, w; };

__device__ __forceinline__ void lds_sync() {
    asm volatile("s_waitcnt lgkmcnt(0)" ::: "memory");
    __builtin_amdgcn_s_barrier();
    asm volatile("" ::: "memory");
}

// ---------- prep 1: K fp32 -> bf16 (row-major) ----------
__global__ __launch_bounds__(256) void cvt_k_kernel(const float* __restrict__ K,
                                                    unsigned short* __restrict__ Kb) {
    size_t i = ((size_t)blockIdx.x * 256 + threadIdx.x) * 8;
    f32x4_t a = *(const f32x4_t*)(K + i);
    f32x4_t b = *(const f32x4_t*)(K + i + 4);
    *(bf16x8_t*)(Kb + i) = pack8(a, b);
}

// ---------- prep 2: V fp32 [bh][k][d] -> bf16 V^T [bh][d][k] ----------
__global__ __launch_bounds__(256) void tr_v_kernel(const float* __restrict__ V,
                                                   unsigned short* __restrict__ VT) {
    __shared__ unsigned short lt[64 * 72];
    const int bh = blockIdx.x >> 5;
    const int kt = blockIdx.x & 31;
    const float* Vb = V + (size_t)bh * (SDIM * DDIM) + (size_t)kt * 64 * DDIM;
    unsigned short* VTb = VT + (size_t)bh * (DDIM * SDIM) + kt * 64;
    const int t = threadIdx.x;
    {
        const int kl = t >> 2, dg = t & 3;
        const float* vp = Vb + kl * DDIM + dg * 16;
        f32x4_t v0 = *(const f32x4_t*)vp;
        f32x4_t v1 = *(const f32x4_t*)(vp + 4);
        f32x4_t v2 = *(const f32x4_t*)(vp + 8);
        f32x4_t v3 = *(const f32x4_t*)(vp + 12);
#pragma unroll
        for (int j = 0; j < 16; ++j) {
            float f = (j < 4) ? v0[j] : (j < 8) ? v1[j - 4] : (j < 12) ? v2[j - 8] : v3[j - 12];
            lt[(dg * 16 + j) * 72 + kl] = f2bf(f);
        }
    }
    __syncthreads();
    {
        const int d = t >> 2, kg = t & 3;
        bf16x8_t w0 = *(const bf16x8_t*)&lt[d * 72 + kg * 16];
        bf16x8_t w1 = *(const bf16x8_t*)&lt[d * 72 + kg * 16 + 8];
        *(bf16x8_t*)(VTb + (size_t)d * SDIM + kg * 16) = w0;
        *(bf16x8_t*)(VTb + (size_t)d * SDIM + kg * 16 + 8) = w1;
    }
}

// ---------- main: chunk-pipelined (passA(c1) fused under passB(c0) stores) ----------
__global__ __launch_bounds__(256, 2) void sdpa_main_kernel(
    const float* __restrict__ Q, const unsigned short* __restrict__ Kb,
    const unsigned short* __restrict__ VT, float* __restrict__ out,
    float* __restrict__ attn)
{
    __shared__ __align__(16) unsigned short Klds[2][KBLK * DDIM];  // 2 x 8KB
    __shared__ __align__(16) unsigned short Vlds[2][KBLK * DDIM];  // 2 x 8KB
    __shared__ __align__(16) float pbuf[4][16 * 64];               // 16KB

    const int bid = blockIdx.x;
    const int bh  = bid >> 4;      // R11 mapping (R12's XCD swizzle regressed -> reverted)
    const int qt  = bid & 15;
    const int tid = threadIdx.x;
    const int lane = tid & 63;
    const int wv   = tid >> 6;     // 0..3
    const int l15  = lane & 15;
    const int hi   = lane >> 4;    // 0..3
    const int qbase = qt * 128 + wv * 32;

    const unsigned short* KbB = Kb + (size_t)bh * (SDIM * DDIM);
    const unsigned short* VTb = VT + (size_t)bh * (DDIM * SDIM);
    float* outW  = out  + ((size_t)bh * SDIM + qbase) * DDIM;
    float* attnW = attn + (size_t)bh * SDIM * SDIM + (size_t)qbase * SDIM;
    float* pb = pbuf[wv];

    const float SC = 0.18033688011112042f;  // (1/sqrt(64)) * log2(e)

    // ---- Q fragments (B operand), 2 sub-tiles, pre-scaled by SC
    const float* qp0 = Q + ((size_t)bh * SDIM + qbase + l15) * DDIM + hi * 8;
    const float* qp1 = qp0 + (size_t)16 * DDIM;
    const bf16x8_t aq0_0 = pack8s(*(const f32x4_t*)qp0,        *(const f32x4_t*)(qp0 + 4), SC);
    const bf16x8_t aq1_0 = pack8s(*(const f32x4_t*)(qp0 + 32), *(const f32x4_t*)(qp0 + 36), SC);
    const bf16x8_t aq0_1 = pack8s(*(const f32x4_t*)qp1,        *(const f32x4_t*)(qp1 + 4), SC);
    const bf16x8_t aq1_1 = pack8s(*(const f32x4_t*)(qp1 + 32), *(const f32x4_t*)(qp1 + 36), SC);

    // ---- staging helpers (contiguous full-line global access; 256 threads)
    auto stage_load_K = [&](int kbase, bf16x8_t kreg[2]) {
#pragma unroll
        for (int j = 0; j < 2; ++j)
            kreg[j] = *(const bf16x8_t*)(KbB + (size_t)kbase * DDIM + (j * 256 + tid) * 8);
    };
    auto stage_write_K = [&](unsigned short* dst, const bf16x8_t kreg[2]) {
#pragma unroll
        for (int j = 0; j < 2; ++j) {
            const int b = (j * 256 + tid) * 16;
            const int row = b >> 7;
            *(bf16x8_t*)((char*)dst + (b ^ ((row & 7) << 4))) = kreg[j];
        }
    };
    auto stage_load_V = [&](int kbase, bf16x8_t vreg[2]) {
#pragma unroll
        for (int j = 0; j < 2; ++j) {
            const int row = j * 32 + (tid >> 3);
            vreg[j] = *(const bf16x8_t*)(VTb + (size_t)row * SDIM + kbase + (tid & 7) * 8);
        }
    };
    auto stage_write_V = [&](unsigned short* dst, const bf16x8_t vreg[2]) {
#pragma unroll
        for (int j = 0; j < 2; ++j) {
            const int row = j * 32 + (tid >> 3);
            const int b = row * 128 + (tid & 7) * 16;
            *(bf16x8_t*)((char*)dst + (b ^ ((row & 7) << 4))) = vreg[j];
        }
    };
    auto read_tile = [&](const unsigned short* src, int s, int c) -> bf16x8_t {
        const int row = s * 16 + l15;
        const int b = row * 128 + c * 64 + hi * 16;
        return *(const bf16x8_t*)((const char*)src + (b ^ ((row & 7) << 4)));
    };

    const int laneA = l15 + ((hi & 1) << 5);
    const int laneB = laneA + 16;
    const bool selHi = (hi >> 1) != 0;

    // p transpose-store through pbuf: full-line global writes (R10-verified)
    auto store_sub = [&](const f32x4_t P[4], int t, int kbase) {
#pragma unroll
        for (int g = 0; g < 4; ++g) {
            const int c4 = (g * 4 + hi) ^ ((l15 & 7) << 1);
            *(f32x4_t*)(pb + l15 * 64 + c4 * 4) = P[g];
        }
        asm volatile("s_waitcnt lgkmcnt(0)" ::: "memory");
        __builtin_amdgcn_sched_barrier(0);
#pragma unroll
        for (int j = 0; j < 4; ++j) {
            const int row = j * 4 + (lane & 3);
            const int c4 = lane >> 2;
            f32x4_t v = *(const f32x4_t*)(pb + row * 64 + (c4 ^ ((row & 7) << 1)) * 4);
            __builtin_nontemporal_store(v,
                (f32x4_t*)(attnW + (size_t)(t * 16 + row) * SDIM + kbase + c4 * 4));
        }
        asm volatile("s_waitcnt lgkmcnt(0)" ::: "memory");
        __builtin_amdgcn_sched_barrier(0);
    };
    // shfl redistribution (R7-verified): P[4 groups] -> af[2]
    auto build_af = [&](const f32x4_t P[4], bf16x8_t af[2]) {
        unsigned int w0[4], w1[4];
#pragma unroll
        for (int s = 0; s < 4; ++s) {
            w0[s] = pack2(P[s][0], P[s][1]);
            w1[s] = pack2(P[s][2], P[s][3]);
        }
#pragma unroll
        for (int k2 = 0; k2 < 2; ++k2) {
            const int sL = 2 * k2, sH = 2 * k2 + 1;
            unsigned int W0a = (unsigned int)__shfl((int)w0[sL], laneA);
            unsigned int W0b = (unsigned int)__shfl((int)w0[sH], laneA);
            unsigned int W1a = (unsigned int)__shfl((int)w1[sL], laneA);
            unsigned int W1b = (unsigned int)__shfl((int)w1[sH], laneA);
            unsigned int W2a = (unsigned int)__shfl((int)w0[sL], laneB);
            unsigned int W2b = (unsigned int)__shfl((int)w0[sH], laneB);
            unsigned int W3a = (unsigned int)__shfl((int)w1[sL], laneB);
            unsigned int W3b = (unsigned int)__shfl((int)w1[sH], laneB);
            uint4s W;
            W.x = selHi ? W0b : W0a;
            W.y = selHi ? W1b : W1a;
            W.z = selHi ? W2b : W2a;
            W.w = selHi ? W3b : W3a;
            af[k2] = __builtin_bit_cast(bf16x8_t, W);
        }
    };

    // ============ phase 1: pass A for chunk 0 only (half-size serial prefix) ============
    float rs0 = 0.f;
    {
        bf16x8_t kreg[2];
        stage_load_K(0, kreg);
        stage_write_K(Klds[0], kreg);
        lds_sync();
        for (int kb = 0; kb < NIT; ++kb) {
            bf16x8_t knx[2];
            if (kb + 1 < NIT) stage_load_K((kb + 1) * KBLK, knx);
            const unsigned short* Kc = Klds[kb & 1];
#pragma unroll
            for (int s = 0; s < 4; ++s) {
                bf16x8_t k0 = read_tile(Kc, s, 0), k1 = read_tile(Kc, s, 1);
                f32x4_t a0 = {0.f,0.f,0.f,0.f};
                a0 = __builtin_amdgcn_mfma_f32_16x16x32_bf16(k0, aq0_0, a0, 0, 0, 0);
                a0 = __builtin_amdgcn_mfma_f32_16x16x32_bf16(k1, aq1_0, a0, 0, 0, 0);
                rs0 += __builtin_amdgcn_exp2f(a0[0]) + __builtin_amdgcn_exp2f(a0[1])
                     + __builtin_amdgcn_exp2f(a0[2]) + __builtin_amdgcn_exp2f(a0[3]);
            }
            if (kb + 1 < NIT) stage_write_K(Klds[(kb + 1) & 1], knx);
            lds_sync();
        }
    }
    rs0 += __shfl_xor(rs0, 16); rs0 += __shfl_xor(rs0, 32);
    const float nlg0 = __builtin_amdgcn_logf(rs0);

    // ============ phase 2: pass B (chunk 0) fused with pass A (chunk 1) ============
    f32x4_t oacc0[4] = {{0.f,0.f,0.f,0.f},{0.f,0.f,0.f,0.f},{0.f,0.f,0.f,0.f},{0.f,0.f,0.f,0.f}};
    float rs1 = 0.f;
    {
        bf16x8_t kreg[2], vreg[2];
        stage_load_K(0, kreg);
        stage_load_V(0, vreg);
        stage_write_K(Klds[0], kreg);
        stage_write_V(Vlds[0], vreg);
        lds_sync();
        for (int kb = 0; kb < NIT; ++kb) {
            const int kbase = kb * KBLK;
            bf16x8_t knx[2], vnx[2];
            if (kb + 1 < NIT) {
                stage_load_K(kbase + KBLK, knx);
                stage_load_V(kbase + KBLK, vnx);
            }
            const unsigned short* Kc = Klds[kb & 1];
            const unsigned short* Vc = Vlds[kb & 1];

            // QK^T chunk0 (kept) + chunk1 (row-sum only), same staged K tile
            f32x4_t A0[4];
#pragma unroll
            for (int s = 0; s < 4; ++s) {
                bf16x8_t k0 = read_tile(Kc, s, 0), k1 = read_tile(Kc, s, 1);
                f32x4_t a0 = {0.f,0.f,0.f,0.f}, a1 = {0.f,0.f,0.f,0.f};
                a0 = __builtin_amdgcn_mfma_f32_16x16x32_bf16(k0, aq0_0, a0, 0, 0, 0);
                a0 = __builtin_amdgcn_mfma_f32_16x16x32_bf16(k1, aq1_0, a0, 0, 0, 0);
                a1 = __builtin_amdgcn_mfma_f32_16x16x32_bf16(k0, aq0_1, a1, 0, 0, 0);
                a1 = __builtin_amdgcn_mfma_f32_16x16x32_bf16(k1, aq1_1, a1, 0, 0, 0);
                A0[s] = a0;
                rs1 += __builtin_amdgcn_exp2f(a1[0]) + __builtin_amdgcn_exp2f(a1[1])
                     + __builtin_amdgcn_exp2f(a1[2]) + __builtin_amdgcn_exp2f(a1[3]);
            }

            f32x4_t P0[4];
#pragma unroll
            for (int s = 0; s < 4; ++s) {
#pragma unroll
                for (int r = 0; r < 4; ++r)
                    P0[s][r] = __builtin_amdgcn_exp2f(A0[s][r] - nlg0);
            }

            bf16x8_t af0[2];
            build_af(P0, af0);
#pragma unroll
            for (int dt = 0; dt < 4; ++dt) {
                bf16x8_t v0 = read_tile(Vc, dt, 0), v1 = read_tile(Vc, dt, 1);
                oacc0[dt] = __builtin_amdgcn_mfma_f32_16x16x32_bf16(af0[0], v0, oacc0[dt], 0, 0, 0);
                oacc0[dt] = __builtin_amdgcn_mfma_f32_16x16x32_bf16(af0[1], v1, oacc0[dt], 0, 0, 0);
            }

            store_sub(P0, 0, kbase);

            if (kb + 1 < NIT) {
                stage_write_K(Klds[(kb + 1) & 1], knx);
                stage_write_V(Vlds[(kb + 1) & 1], vnx);
            }
            lds_sync();
        }
    }
    rs1 += __shfl_xor(rs1, 16); rs1 += __shfl_xor(rs1, 32);
    const float nlg1 = __builtin_amdgcn_logf(rs1);

    // ============ phase 3: pass B (chunk 1) ============
    f32x4_t oacc1[4] = {{0.f,0.f,0.f,0.f},{0.f,0.f,0.f,0.f},{0.f,0.f,0.f,0.f},{0.f,0.f,0.f,0.f}};
    {
        bf16x8_t kreg[2], vreg[2];
        stage_load_K(0, kreg);
        stage_load_V(0, vreg);
        stage_write_K(Klds[0], kreg);
        stage_write_V(Vlds[0], vreg);
        lds_sync();
        for (int kb = 0; kb < NIT; ++kb) {
            const int kbase = kb * KBLK;
            bf16x8_t knx[2], vnx[2];
            if (kb + 1 < NIT) {
                stage_load_K(kbase + KBLK, knx);
                stage_load_V(kbase + KBLK, vnx);
            }
            const unsigned short* Kc = Klds[kb & 1];
            const unsigned short* Vc = Vlds[kb & 1];

            f32x4_t A1[4];
#pragma unroll
            for (int s = 0; s < 4; ++s) {
                bf16x8_t k0 = read_tile(Kc, s, 0), k1 = read_tile(Kc, s, 1);
                f32x4_t a1 = {0.f,0.f,0.f,0.f};
                a1 = __builtin_amdgcn_mfma_f32_16x16x32_bf16(k0, aq0_1, a1, 0, 0, 0);
                a1 = __builtin_amdgcn_mfma_f32_16x16x32_bf16(k1, aq1_1, a1, 0, 0, 0);
                A1[s] = a1;
            }

            f32x4_t P1[4];
#pragma unroll
            for (int s = 0; s < 4; ++s) {
#pragma unroll
                for (int r = 0; r < 4; ++r)
                    P1[s][r] = __builtin_amdgcn_exp2f(A1[s][r] - nlg1);
            }

            bf16x8_t af1[2];
            build_af(P1, af1);
#pragma unroll
            for (int dt = 0; dt < 4; ++dt) {
                bf16x8_t v0 = read_tile(Vc, dt, 0), v1 = read_tile(Vc, dt, 1);
                oacc1[dt] = __builtin_amdgcn_mfma_f32_16x16x32_bf16(af1[0], v0, oacc1[dt], 0, 0, 0);
                oacc1[dt] = __builtin_amdgcn_mfma_f32_16x16x32_bf16(af1[1], v1, oacc1[dt], 0, 0, 0);
            }

            store_sub(P1, 1, kbase);

            if (kb + 1 < NIT) {
                stage_write_K(Klds[(kb + 1) & 1], knx);
                stage_write_V(Vlds[(kb + 1) & 1], vnx);
            }
            lds_sync();
        }
    }

    // --- epilogue: output (normalized)
#pragma unroll
    for (int dt = 0; dt < 4; ++dt) {
#pragma unroll
        for (int r = 0; r < 4; ++r) {
            outW[(size_t)(hi * 4 + r) * DDIM + dt * 16 + l15] = oacc0[dt][r];
            outW[(size_t)(16 + hi * 4 + r) * DDIM + dt * 16 + l15] = oacc1[dt][r];
        }
    }
}

extern "C" void kernel_launch(void* const* d_in, const int* in_sizes, int n_in,
                              void* d_out, int out_size, void* d_ws, size_t ws_size,
                              hipStream_t stream) {
    const float* Q = (const float*)d_in[0];
    const float* K = (const float*)d_in[1];
    const float* V = (const float*)d_in[2];
    float* out  = (float*)d_out;
    float* attn = out + (size_t)NBH * SDIM * DDIM;

    unsigned short* Kb = (unsigned short*)d_ws;
    unsigned short* VT = Kb + (size_t)NBH * SDIM * DDIM;

    cvt_k_kernel<<<dim3((NBH * SDIM * DDIM) / (256 * 8)), dim3(256), 0, stream>>>(K, Kb);
    tr_v_kernel<<<dim3(NBH * 32), dim3(256), 0, stream>>>(V, VT);

    sdpa_main_kernel<<<dim3(NBH * 16), dim3(256), 0, stream>>>(Q, Kb, VT, out, attn);
}